// Round 7
// baseline (690.435 us; speedup 1.0000x reference)
//
#include <hip/hip_runtime.h>
#include <hip/hip_fp16.h>

#define N_NODES 50000
#define N_EDGES 1600000
#define F_IN 8
#define F_OUT 12
#define PERIODS 6
#define FP 48                       // F_IN * PERIODS
#define BKT_SH 6                    // 64 nodes per bucket
#define BKT_N 64
#define NBKT ((N_NODES + BKT_N - 1) / BKT_N)   // 782
#define CHK 8192
#define NCHK ((N_EDGES + CHK - 1) / CHK)       // 196
#define SRC_MASK 0x1FFFFu           // src < 50000 < 2^17
#define XROW 49                     // padded LDS row stride (odd -> banks spread)

// ---- pass 1: per-chunk LDS histogram over buckets + per-edge local rank ----
__global__ void __launch_bounds__(256) k_hist(const int* __restrict__ dst,
                                              unsigned short* __restrict__ lrank,
                                              unsigned int* __restrict__ hist) {
    __shared__ unsigned int h[NBKT];
    int tid = threadIdx.x, blk = blockIdx.x;
    for (int k = tid; k < NBKT; k += 256) h[k] = 0u;
    __syncthreads();
    int base = blk * CHK;
    for (int i = tid; i < CHK; i += 256) {
        int e = base + i;
        if (e < N_EDGES)
            lrank[e] = (unsigned short)atomicAdd(&h[dst[e] >> BKT_SH], 1u);
    }
    __syncthreads();
    for (int k = tid; k < NBKT; k += 256) hist[(size_t)blk * NBKT + k] = h[k];
}

// ---- pass 2a: per-bucket exclusive scan over the 196 chunks ----
__global__ void __launch_bounds__(256) k_colscan(const unsigned int* __restrict__ hist,
                                                 unsigned int* __restrict__ colpre,
                                                 unsigned int* __restrict__ tot) {
    __shared__ unsigned int arr[256];
    int t = threadIdx.x, k = blockIdx.x;
    unsigned int v = (t < NCHK) ? hist[(size_t)t * NBKT + k] : 0u;
    arr[t] = v;
    __syncthreads();
    for (int off = 1; off < 256; off <<= 1) {
        unsigned int u = (t >= off) ? arr[t - off] : 0u;
        __syncthreads();
        arr[t] += u;
        __syncthreads();
    }
    if (t < NCHK) colpre[(size_t)t * NBKT + k] = arr[t] - v;  // exclusive
    if (t == NCHK - 1) tot[k] = arr[t];                        // bucket total
}

// ---- pass 2b: exclusive scan of 782 bucket totals ----
__global__ void __launch_bounds__(1024) k_topscan(const unsigned int* __restrict__ tot,
                                                  unsigned int* __restrict__ bktstart) {
    __shared__ unsigned int arr[1024];
    int t = threadIdx.x;
    unsigned int v = (t < NBKT) ? tot[t] : 0u;
    arr[t] = v;
    __syncthreads();
    for (int off = 1; off < 1024; off <<= 1) {
        unsigned int u = (t >= off) ? arr[t - off] : 0u;
        __syncthreads();
        arr[t] += u;
        __syncthreads();
    }
    if (t < NBKT) bktstart[t] = arr[t] - v;  // exclusive
    if (t == NBKT - 1) bktstart[NBKT] = arr[t];
}

// ---- pass 3: scatter edges to bucket segments (deterministic, NO atomics) ----
// entry: hi32 = ew bits, lo32 = (d&63)<<24 | src
__global__ void __launch_bounds__(256) k_scatter(const int* __restrict__ src,
                                                 const int* __restrict__ dst,
                                                 const float* __restrict__ ew,
                                                 const unsigned short* __restrict__ lrank,
                                                 const unsigned int* __restrict__ colpre,
                                                 const unsigned int* __restrict__ bktstart,
                                                 unsigned long long* __restrict__ part) {
    __shared__ unsigned int ldsOff[NBKT];
    int tid = threadIdx.x, blk = blockIdx.x;
    for (int k = tid; k < NBKT; k += 256)
        ldsOff[k] = bktstart[k] + colpre[(size_t)blk * NBKT + k];
    __syncthreads();
    int base = blk * CHK;
    for (int i = tid; i < CHK; i += 256) {
        int e = base + i;
        if (e >= N_EDGES) continue;
        int s = src[e], d = dst[e];
        unsigned int pos = ldsOff[d >> BKT_SH] + (unsigned int)lrank[e];
        unsigned int lo = ((unsigned int)(d & (BKT_N - 1)) << 24) | (unsigned int)s;
        part[pos] = ((unsigned long long)__float_as_uint(ew[e]) << 32) | lo;
    }
}

// ---- pass 4: per-bucket streaming deg -> dinv (no sort needed) ----
__global__ void __launch_bounds__(256) k_deg(const unsigned long long* __restrict__ part,
                                             const unsigned int* __restrict__ bktstart,
                                             float* __restrict__ dinv) {
    __shared__ float degl[BKT_N];
    int tid = threadIdx.x, k = blockIdx.x;
    if (tid < BKT_N) degl[tid] = 1.0f;  // self loop
    __syncthreads();
    unsigned int b = bktstart[k], e = bktstart[k + 1];
    for (unsigned int i = b + tid; i < e; i += 256) {
        unsigned long long p = part[i];
        atomicAdd(&degl[((unsigned int)p >> 24) & (BKT_N - 1)],
                  __uint_as_float((unsigned int)(p >> 32)));
    }
    __syncthreads();
    int n = k * BKT_N + tid;
    if (tid < BKT_N && n < N_NODES) dinv[n] = rsqrtf(degl[tid]);
}

// ---- pass 5: xs[n] = fp16(dinv[n] * x[n])  (4.8 MB, near L2-resident) ----
__global__ void k_xs(const float* __restrict__ x, const float* __restrict__ dinv,
                     uint4* __restrict__ xs) {
    int t = blockIdx.x * blockDim.x + threadIdx.x;
    if (t >= N_NODES * 6) return;
    int n = t / 6, c = t % 6;
    float di = dinv[n];
    const float4* xr = (const float4*)(x + (size_t)n * FP + c * 8);
    float4 a = xr[0], b = xr[1];
    __half2 h0 = __floats2half2_rn(di * a.x, di * a.y);
    __half2 h1 = __floats2half2_rn(di * a.z, di * a.w);
    __half2 h2 = __floats2half2_rn(di * b.x, di * b.y);
    __half2 h3 = __floats2half2_rn(di * b.z, di * b.w);
    uint4 o;
    o.x = *(unsigned int*)&h0; o.y = *(unsigned int*)&h1;
    o.z = *(unsigned int*)&h2; o.w = *(unsigned int*)&h3;
    xs[t] = o;
}

// ---- pass 6: per-bucket LDS-accumulate + fused epilogue, writes out directly ----
// xagg[n] = dinv[n] * (xs[n] + sum_{e: dst=n} ew_e * xs[src_e])
__global__ void __launch_bounds__(256) k_mega(const uint4* __restrict__ xs,
                                              const float* __restrict__ dinv,
                                              const unsigned long long* __restrict__ part,
                                              const unsigned int* __restrict__ bktstart,
                                              const float* __restrict__ att,
                                              const float* __restrict__ Wz, const float* __restrict__ bz,
                                              const float* __restrict__ Wh, const float* __restrict__ bh,
                                              const float* __restrict__ lzW, const float* __restrict__ lzb,
                                              const float* __restrict__ lhW, const float* __restrict__ lhb,
                                              const float* __restrict__ linW, const float* __restrict__ linb,
                                              float* __restrict__ out) {
    __shared__ float xacc[BKT_N * XROW];
    int tid = threadIdx.x, k = blockIdx.x;
    for (int i = tid; i < BKT_N * XROW; i += 256) xacc[i] = 0.f;
    __syncthreads();
    unsigned int b = bktstart[k], e = bktstart[k + 1];
    for (unsigned int i = b + tid; i < e; i += 256) {
        unsigned long long p = part[i];
        unsigned int lo = (unsigned int)p;
        float w = __uint_as_float((unsigned int)(p >> 32));
        int s = (int)(lo & SRC_MASK);
        int base = (int)((lo >> 24) & (BKT_N - 1)) * XROW;
        const uint4* xp = xs + (size_t)s * 6;
        #pragma unroll
        for (int j = 0; j < 6; j++) {
            uint4 v = xp[j];
            __half2* hp = (__half2*)&v;
            #pragma unroll
            for (int q = 0; q < 4; q++) {
                float2 f = __half22float2(hp[q]);
                atomicAdd(&xacc[base + j * 8 + q * 2],     w * f.x);
                atomicAdd(&xacc[base + j * 8 + q * 2 + 1], w * f.y);
            }
        }
    }
    __syncthreads();
    int n = k * BKT_N + tid;
    if (tid >= BKT_N || n >= N_NODES) return;

    float di = dinv[n];
    float row[FP];
    {
        const uint4* xp = xs + (size_t)n * 6;
        #pragma unroll
        for (int j = 0; j < 6; j++) {
            uint4 v = xp[j];
            __half2* hp = (__half2*)&v;
            #pragma unroll
            for (int q = 0; q < 4; q++) {
                float2 f = __half22float2(hp[q]);
                row[j * 8 + q * 2]     = di * (f.x + xacc[tid * XROW + j * 8 + q * 2]);
                row[j * 8 + q * 2 + 1] = di * (f.y + xacc[tid * XROW + j * 8 + q * 2 + 1]);
            }
        }
    }

    // softmax(att)
    float a[PERIODS];
    float m = -1e30f;
    #pragma unroll
    for (int p = 0; p < PERIODS; p++) { a[p] = att[p]; m = fmaxf(m, a[p]); }
    float se = 0.f;
    #pragma unroll
    for (int p = 0; p < PERIODS; p++) { a[p] = __expf(a[p] - m); se += a[p]; }
    float inv = 1.f / se;
    #pragma unroll
    for (int p = 0; p < PERIODS; p++) a[p] *= inv;

    // H0 == 0 => R gate dead; Z/Ht use only first F_OUT cols of lzW/lhW.
    float H[F_OUT];
    #pragma unroll
    for (int j = 0; j < F_OUT; j++) H[j] = 0.f;

    for (int p = 0; p < PERIODS; p++) {
        float gz[F_OUT], gh[F_OUT];
        #pragma unroll
        for (int j = 0; j < F_OUT; j++) { gz[j] = bz[j]; gh[j] = bh[j]; }
        #pragma unroll
        for (int f = 0; f < F_IN; f++) {
            float xv = row[f * PERIODS + p];
            #pragma unroll
            for (int j = 0; j < F_OUT; j++) {
                gz[j] += xv * Wz[f * F_OUT + j];
                gh[j] += xv * Wh[f * F_OUT + j];
            }
        }
        #pragma unroll
        for (int j = 0; j < F_OUT; j++) {
            float z = lzb[j], t2 = lhb[j];
            #pragma unroll
            for (int kk = 0; kk < F_OUT; kk++) {
                z  += gz[kk] * lzW[j * (2 * F_OUT) + kk];
                t2 += gh[kk] * lhW[j * (2 * F_OUT) + kk];
            }
            float Z = 1.f / (1.f + __expf(-z));
            H[j] += a[p] * (1.f - Z) * tanhf(t2);
        }
    }

    float* op = out + (size_t)n * PERIODS;
    #pragma unroll
    for (int q = 0; q < PERIODS; q++) {
        float acc = linb[q];
        #pragma unroll
        for (int j = 0; j < F_OUT; j++)
            acc += fmaxf(H[j], 0.f) * linW[q * F_OUT + j];
        op[q] = acc;
    }
}

extern "C" void kernel_launch(void* const* d_in, const int* in_sizes, int n_in,
                              void* d_out, int out_size, void* d_ws, size_t ws_size,
                              hipStream_t stream) {
    const float* x    = (const float*)d_in[0];
    const int*   ei   = (const int*)d_in[1];
    const float* ew   = (const float*)d_in[2];
    const float* att  = (const float*)d_in[3];
    const float* Wz   = (const float*)d_in[4];
    const float* bz   = (const float*)d_in[5];
    // d_in[6]=Wr, d_in[7]=br : dead (H0 == 0)
    const float* Wh   = (const float*)d_in[8];
    const float* bh   = (const float*)d_in[9];
    const float* lzW  = (const float*)d_in[10];
    const float* lzb  = (const float*)d_in[11];
    // d_in[12]=lrW, d_in[13]=lrb : dead
    const float* lhW  = (const float*)d_in[14];
    const float* lhb  = (const float*)d_in[15];
    const float* linW = (const float*)d_in[16];
    const float* linb = (const float*)d_in[17];
    float* out = (float*)d_out;

    // ws layout (no overlays; ~22.3 MB total)
    unsigned long long* part = (unsigned long long*)d_ws;            // E * 8B
    uint4* xs = (uint4*)(part + N_EDGES);                            // N*6 uint4 (fp16 x*dinv)
    unsigned short* lrank = (unsigned short*)(xs + (size_t)N_NODES * 6); // E u16
    unsigned int* hist   = (unsigned int*)(lrank + N_EDGES);         // NCHK*NBKT u32
    unsigned int* colpre = hist + (size_t)NCHK * NBKT;               // NCHK*NBKT u32
    float* dinv = (float*)(colpre + (size_t)NCHK * NBKT);            // N floats
    unsigned int* bktstart = (unsigned int*)(dinv + N_NODES);        // NBKT+1 u32
    unsigned int* tot = bktstart + NBKT + 1;                         // NBKT u32

    const int* srcp = ei;
    const int* dstp = ei + N_EDGES;

    k_hist<<<NCHK, 256, 0, stream>>>(dstp, lrank, hist);
    k_colscan<<<NBKT, 256, 0, stream>>>(hist, colpre, tot);
    k_topscan<<<1, 1024, 0, stream>>>(tot, bktstart);
    k_scatter<<<NCHK, 256, 0, stream>>>(srcp, dstp, ew, lrank, colpre, bktstart, part);
    k_deg<<<NBKT, 256, 0, stream>>>(part, bktstart, dinv);
    k_xs<<<(N_NODES * 6 + 255) / 256, 256, 0, stream>>>(x, dinv, xs);
    k_mega<<<NBKT, 256, 0, stream>>>(xs, dinv, part, bktstart, att, Wz, bz, Wh, bh,
                                     lzW, lzb, lhW, lhb, linW, linb, out);
}

// Round 8
// 246.735 us; speedup vs baseline: 2.7983x; 2.7983x over previous
//
#include <hip/hip_runtime.h>
#include <hip/hip_fp16.h>

#define N_NODES 50000
#define N_EDGES 1600000
#define F_IN 8
#define F_OUT 12
#define PERIODS 6
#define FP 48                      // F_IN * PERIODS
#define BKT_SH 7                   // 128 nodes per bucket
#define BKT_N 128
#define NBKT ((N_NODES + BKT_N - 1) / BKT_N)   // 391
#define CHK 4096
#define NCHK ((N_EDGES + CHK - 1) / CHK)       // 391
#define SEG_CAP 4736               // mean 4096, sigma ~64, +10 sigma
#define SRC_MASK 0x1FFFFu          // src < 50000 < 2^17
#define GN 32                      // nodes per gather block
#define GT 192                     // gather block threads (6 per node)

// ---- pass 1: per-chunk LDS histogram over buckets + per-edge local rank ----
__global__ void __launch_bounds__(256) k_hist(const int* __restrict__ dst,
                                              unsigned short* __restrict__ lrank,
                                              unsigned int* __restrict__ hist) {
    __shared__ unsigned int h[NBKT];
    int tid = threadIdx.x, blk = blockIdx.x;
    for (int k = tid; k < NBKT; k += 256) h[k] = 0u;
    __syncthreads();
    int base = blk * CHK;
    for (int i = tid; i < CHK; i += 256) {
        int e = base + i;
        if (e < N_EDGES)
            lrank[e] = (unsigned short)atomicAdd(&h[dst[e] >> BKT_SH], 1u);
    }
    __syncthreads();
    for (int k = tid; k < NBKT; k += 256) hist[(size_t)blk * NBKT + k] = h[k];
}

// ---- pass 2a: per-bucket column exclusive scan over chunks ----
__global__ void __launch_bounds__(512) k_colscan(const unsigned int* __restrict__ hist,
                                                 unsigned int* __restrict__ colpre,
                                                 unsigned int* __restrict__ tot) {
    __shared__ unsigned int arr[512];
    int t = threadIdx.x, k = blockIdx.x;
    unsigned int v = (t < NCHK) ? hist[(size_t)t * NBKT + k] : 0u;
    arr[t] = v;
    __syncthreads();
    for (int off = 1; off < 512; off <<= 1) {
        unsigned int u = (t >= off) ? arr[t - off] : 0u;
        __syncthreads();
        arr[t] += u;
        __syncthreads();
    }
    if (t < NCHK) colpre[(size_t)t * NBKT + k] = arr[t] - v;   // exclusive
    if (t == NCHK - 1) tot[k] = arr[t];                        // bucket total
}

// ---- pass 2b: exclusive scan of bucket totals ----
__global__ void __launch_bounds__(512) k_topscan(const unsigned int* __restrict__ tot,
                                                 unsigned int* __restrict__ bktstart) {
    __shared__ unsigned int arr[512];
    int t = threadIdx.x;
    unsigned int v = (t < NBKT) ? tot[t] : 0u;
    arr[t] = v;
    __syncthreads();
    for (int off = 1; off < 512; off <<= 1) {
        unsigned int u = (t >= off) ? arr[t - off] : 0u;
        __syncthreads();
        arr[t] += u;
        __syncthreads();
    }
    if (t < NBKT) bktstart[t] = arr[t] - v;  // exclusive
    if (t == NBKT - 1) bktstart[NBKT] = arr[t];
}

// ---- pass 3: scatter edges to bucket segments (deterministic, NO atomics) ----
// entry: hi32 = ew bits, lo32 = (d&127)<<24 | src
__global__ void __launch_bounds__(256) k_scatter(const int* __restrict__ src,
                                                 const int* __restrict__ dst,
                                                 const float* __restrict__ ew,
                                                 const unsigned short* __restrict__ lrank,
                                                 const unsigned int* __restrict__ colpre,
                                                 const unsigned int* __restrict__ bktstart,
                                                 unsigned long long* __restrict__ part) {
    __shared__ unsigned int ldsOff[NBKT];
    int tid = threadIdx.x, blk = blockIdx.x;
    for (int k = tid; k < NBKT; k += 256)
        ldsOff[k] = bktstart[k] + colpre[(size_t)blk * NBKT + k];
    __syncthreads();
    int base = blk * CHK;
    for (int i = tid; i < CHK; i += 256) {
        int e = base + i;
        if (e >= N_EDGES) continue;
        int s = src[e], d = dst[e];
        unsigned int pos = ldsOff[d >> BKT_SH] + (unsigned int)lrank[e];
        unsigned int lo = ((unsigned int)(d & (BKT_N - 1)) << 24) | (unsigned int)s;
        part[pos] = ((unsigned long long)__float_as_uint(ew[e]) << 32) | lo;
    }
}

// ---- pass 4: per-bucket LDS counting sort + deg/dinv + fp16 xs, all fused ----
__global__ void __launch_bounds__(256) k_bucket(unsigned long long* __restrict__ part,
                                                const unsigned int* __restrict__ bktstart,
                                                const float* __restrict__ x,
                                                int* __restrict__ offs,
                                                float* __restrict__ dinv_g,
                                                uint4* __restrict__ xs) {
    __shared__ uint2 stage[SEG_CAP];
    __shared__ unsigned int cnt[BKT_N], cnt2[BKT_N], rowstart[BKT_N], sc[BKT_N];
    __shared__ float degf[BKT_N], dinv_l[BKT_N];
    int tid = threadIdx.x, k = blockIdx.x;
    unsigned int base = bktstart[k];
    unsigned int m = bktstart[k + 1] - base;
    if (m > SEG_CAP) m = SEG_CAP;  // 10-sigma margin; memory safety only
    if (tid < BKT_N) { cnt[tid] = 0u; cnt2[tid] = 0u; degf[tid] = 1.0f; }  // self loop
    __syncthreads();
    // load segment to LDS + count + accumulate deg
    for (unsigned int i = tid; i < m; i += 256) {
        unsigned long long p = part[base + i];
        unsigned int lo = (unsigned int)p;
        unsigned int hi = (unsigned int)(p >> 32);
        stage[i] = make_uint2(lo, hi);
        unsigned int j = (lo >> 24) & (BKT_N - 1);
        atomicAdd(&cnt[j], 1u);
        atomicAdd(&degf[j], __uint_as_float(hi));
    }
    __syncthreads();
    // exclusive scan of 128 counts
    if (tid < BKT_N) sc[tid] = cnt[tid];
    __syncthreads();
    for (int off = 1; off < BKT_N; off <<= 1) {
        unsigned int u = (tid >= (unsigned)off && tid < BKT_N) ? sc[tid - off] : 0u;
        __syncthreads();
        if (tid < BKT_N) sc[tid] += u;
        __syncthreads();
    }
    if (tid < BKT_N) rowstart[tid] = sc[tid] - cnt[tid];
    __syncthreads();

    int n0 = k * BKT_N;
    int nn = N_NODES - n0; if (nn > BKT_N) nn = BKT_N;

    // dinv + offs
    if (tid < BKT_N) {
        float dv = rsqrtf(degf[tid]);
        dinv_l[tid] = dv;
        if (tid < nn) {
            dinv_g[n0 + tid] = dv;
            offs[n0 + tid] = (int)(base + rowstart[tid]);
        }
    }
    if (k == NBKT - 1 && tid == 0) offs[N_NODES] = N_EDGES;

    // sorted in-place write (reads from LDS stage — no hazard)
    for (unsigned int i = tid; i < m; i += 256) {
        uint2 v = stage[i];
        unsigned int j = (v.x >> 24) & (BKT_N - 1);
        unsigned int r = atomicAdd(&cnt2[j], 1u);
        part[base + rowstart[j] + r] = ((unsigned long long)v.y << 32) | v.x;
    }
    __syncthreads();  // dinv_l ready for xs (already synced above, but keep ordering clear)

    // xs[n] = fp16(dinv[n] * x[n]) for this bucket's nodes (coalesced)
    for (int idx = tid; idx < nn * 6; idx += 256) {
        int j = idx / 6, c = idx % 6;
        int n = n0 + j;
        float di = dinv_l[j];
        const float4* xr = (const float4*)(x + (size_t)n * FP + c * 8);
        float4 a = xr[0], b2 = xr[1];
        __half2 h0 = __floats2half2_rn(di * a.x, di * a.y);
        __half2 h1 = __floats2half2_rn(di * a.z, di * a.w);
        __half2 h2 = __floats2half2_rn(di * b2.x, di * b2.y);
        __half2 h3 = __floats2half2_rn(di * b2.z, di * b2.w);
        uint4 o;
        o.x = *(unsigned int*)&h0; o.y = *(unsigned int*)&h1;
        o.z = *(unsigned int*)&h2; o.w = *(unsigned int*)&h3;
        xs[(size_t)n * 6 + c] = o;
    }
}

// ---- pass 5: fused gather (register accumulate) + epilogue ----
// row[n] = dinv[n] * (xs[n] + sum_{e:dst=n} ew_e * xs[src_e]); then gates/att/linear.
__global__ void __launch_bounds__(GT) k_gather_node(
        const uint4* __restrict__ xs, const float* __restrict__ dinv,
        const int* __restrict__ offs, const unsigned long long* __restrict__ part,
        const float* __restrict__ att,
        const float* __restrict__ Wz, const float* __restrict__ bz,
        const float* __restrict__ Wh, const float* __restrict__ bh,
        const float* __restrict__ lzW, const float* __restrict__ lzb,
        const float* __restrict__ lhW, const float* __restrict__ lhb,
        const float* __restrict__ linW, const float* __restrict__ linb,
        float* __restrict__ out) {
    __shared__ float xrow[GN][FP + 1];
    int tid = threadIdx.x;
    int nl = tid / 6, c = tid % 6;        // nl in [0,32), c in [0,6)
    int n = blockIdx.x * GN + nl;
    if (nl < GN && n < N_NODES) {
        float acc[8];
        uint4 self = xs[(size_t)n * 6 + c];
        {
            __half2* hp = (__half2*)&self;
            #pragma unroll
            for (int q = 0; q < 4; q++) {
                float2 f = __half22float2(hp[q]);
                acc[q * 2] = f.x; acc[q * 2 + 1] = f.y;
            }
        }
        int b = offs[n], e = offs[n + 1];
        for (int kk = b; kk < e; kk++) {
            unsigned long long p = part[kk];
            float w = __uint_as_float((unsigned int)(p >> 32));
            int s = (int)((unsigned int)p & SRC_MASK);
            uint4 v = xs[(size_t)s * 6 + c];
            __half2* hp = (__half2*)&v;
            #pragma unroll
            for (int q = 0; q < 4; q++) {
                float2 f = __half22float2(hp[q]);
                acc[q * 2]     += w * f.x;
                acc[q * 2 + 1] += w * f.y;
            }
        }
        float di = dinv[n];
        #pragma unroll
        for (int q = 0; q < 8; q++) xrow[nl][c * 8 + q] = di * acc[q];
    }
    __syncthreads();
    if (tid >= GN) return;
    int n2 = blockIdx.x * GN + tid;
    if (n2 >= N_NODES) return;

    // softmax(att)
    float a[PERIODS];
    float mm = -1e30f;
    #pragma unroll
    for (int p = 0; p < PERIODS; p++) { a[p] = att[p]; mm = fmaxf(mm, a[p]); }
    float se = 0.f;
    #pragma unroll
    for (int p = 0; p < PERIODS; p++) { a[p] = __expf(a[p] - mm); se += a[p]; }
    float inv = 1.f / se;
    #pragma unroll
    for (int p = 0; p < PERIODS; p++) a[p] *= inv;

    const float* row = xrow[tid];

    // H0 == 0 => R gate dead; Z/Ht use only first F_OUT cols of lzW/lhW.
    float H[F_OUT];
    #pragma unroll
    for (int j = 0; j < F_OUT; j++) H[j] = 0.f;

    for (int p = 0; p < PERIODS; p++) {
        float gz[F_OUT], gh[F_OUT];
        #pragma unroll
        for (int j = 0; j < F_OUT; j++) { gz[j] = bz[j]; gh[j] = bh[j]; }
        #pragma unroll
        for (int f = 0; f < F_IN; f++) {
            float xv = row[f * PERIODS + p];
            #pragma unroll
            for (int j = 0; j < F_OUT; j++) {
                gz[j] += xv * Wz[f * F_OUT + j];
                gh[j] += xv * Wh[f * F_OUT + j];
            }
        }
        #pragma unroll
        for (int j = 0; j < F_OUT; j++) {
            float z = lzb[j], t2 = lhb[j];
            #pragma unroll
            for (int kk = 0; kk < F_OUT; kk++) {
                z  += gz[kk] * lzW[j * (2 * F_OUT) + kk];
                t2 += gh[kk] * lhW[j * (2 * F_OUT) + kk];
            }
            float Z = 1.f / (1.f + __expf(-z));
            H[j] += a[p] * (1.f - Z) * tanhf(t2);
        }
    }

    float* op = out + (size_t)n2 * PERIODS;
    #pragma unroll
    for (int q = 0; q < PERIODS; q++) {
        float acc2 = linb[q];
        #pragma unroll
        for (int j = 0; j < F_OUT; j++)
            acc2 += fmaxf(H[j], 0.f) * linW[q * F_OUT + j];
        op[q] = acc2;
    }
}

extern "C" void kernel_launch(void* const* d_in, const int* in_sizes, int n_in,
                              void* d_out, int out_size, void* d_ws, size_t ws_size,
                              hipStream_t stream) {
    const float* x    = (const float*)d_in[0];
    const int*   ei   = (const int*)d_in[1];
    const float* ew   = (const float*)d_in[2];
    const float* att  = (const float*)d_in[3];
    const float* Wz   = (const float*)d_in[4];
    const float* bz   = (const float*)d_in[5];
    // d_in[6]=Wr, d_in[7]=br : dead (H0 == 0)
    const float* Wh   = (const float*)d_in[8];
    const float* bh   = (const float*)d_in[9];
    const float* lzW  = (const float*)d_in[10];
    const float* lzb  = (const float*)d_in[11];
    // d_in[12]=lrW, d_in[13]=lrb : dead
    const float* lhW  = (const float*)d_in[14];
    const float* lhb  = (const float*)d_in[15];
    const float* linW = (const float*)d_in[16];
    const float* linb = (const float*)d_in[17];
    float* out = (float*)d_out;

    // ws layout (~22 MB)
    unsigned long long* part = (unsigned long long*)d_ws;            // E * 8B (sorted in place)
    uint4* xs = (uint4*)(part + N_EDGES);                            // N*6 uint4 (fp16 dinv*x)
    unsigned short* lrank = (unsigned short*)(xs + (size_t)N_NODES * 6); // E u16
    unsigned int* hist   = (unsigned int*)(lrank + N_EDGES);         // NCHK*NBKT u32
    unsigned int* colpre = hist + (size_t)NCHK * NBKT;               // NCHK*NBKT u32
    float* dinv = (float*)(colpre + (size_t)NCHK * NBKT);            // N floats
    int*   offs = (int*)(dinv + N_NODES);                            // N+1 ints
    unsigned int* bktstart = (unsigned int*)(offs + N_NODES + 1);    // NBKT+1 u32
    unsigned int* tot = bktstart + NBKT + 1;                         // NBKT u32

    const int* srcp = ei;
    const int* dstp = ei + N_EDGES;

    k_hist<<<NCHK, 256, 0, stream>>>(dstp, lrank, hist);
    k_colscan<<<NBKT, 512, 0, stream>>>(hist, colpre, tot);
    k_topscan<<<1, 512, 0, stream>>>(tot, bktstart);
    k_scatter<<<NCHK, 256, 0, stream>>>(srcp, dstp, ew, lrank, colpre, bktstart, part);
    k_bucket<<<NBKT, 256, 0, stream>>>(part, bktstart, x, offs, dinv, xs);
    k_gather_node<<<(N_NODES + GN - 1) / GN, GT, 0, stream>>>(
        xs, dinv, offs, part, att, Wz, bz, Wh, bh,
        lzW, lzb, lhW, lhb, linW, linb, out);
}

// Round 9
// 241.822 us; speedup vs baseline: 2.8551x; 1.0203x over previous
//
#include <hip/hip_runtime.h>
#include <hip/hip_fp16.h>

#define N_NODES 50000
#define N_EDGES 1600000
#define F_IN 8
#define F_OUT 12
#define PERIODS 6
#define FP 48                      // F_IN * PERIODS
#define BKT_SH 7                   // 128 nodes per bucket
#define BKT_N 128
#define NBKT ((N_NODES + BKT_N - 1) / BKT_N)   // 391
#define CHK 4096
#define NCHK ((N_EDGES + CHK - 1) / CHK)       // 391
#define SEG_CAP 4736               // mean 4096, sigma ~64, +10 sigma
#define SRC_MASK 0x1FFFFu          // src < 50000 < 2^17

// ---- pass 1: per-chunk LDS histogram over buckets (no rank output) ----
__global__ void __launch_bounds__(256) k_hist(const int* __restrict__ dst,
                                              unsigned int* __restrict__ hist) {
    __shared__ unsigned int h[NBKT];
    int tid = threadIdx.x, blk = blockIdx.x;
    for (int k = tid; k < NBKT; k += 256) h[k] = 0u;
    __syncthreads();
    int base = blk * CHK;
    for (int i = tid; i < CHK; i += 256) {
        int e = base + i;
        if (e < N_EDGES) atomicAdd(&h[dst[e] >> BKT_SH], 1u);
    }
    __syncthreads();
    for (int k = tid; k < NBKT; k += 256) hist[(size_t)blk * NBKT + k] = h[k];
}

// ---- pass 2a: per-bucket column exclusive scan over chunks, IN PLACE on hist ----
__global__ void __launch_bounds__(512) k_colscan(unsigned int* __restrict__ hist,
                                                 unsigned int* __restrict__ tot) {
    __shared__ unsigned int arr[512];
    int t = threadIdx.x, k = blockIdx.x;
    unsigned int v = (t < NCHK) ? hist[(size_t)t * NBKT + k] : 0u;
    arr[t] = v;
    __syncthreads();
    for (int off = 1; off < 512; off <<= 1) {
        unsigned int u = (t >= off) ? arr[t - off] : 0u;
        __syncthreads();
        arr[t] += u;
        __syncthreads();
    }
    if (t < NCHK) hist[(size_t)t * NBKT + k] = arr[t] - v;  // exclusive (colpre)
    if (t == NCHK - 1) tot[k] = arr[t];                     // bucket total
}

// ---- pass 2b: exclusive scan of bucket totals ----
__global__ void __launch_bounds__(512) k_topscan(const unsigned int* __restrict__ tot,
                                                 unsigned int* __restrict__ bktstart) {
    __shared__ unsigned int arr[512];
    int t = threadIdx.x;
    unsigned int v = (t < NBKT) ? tot[t] : 0u;
    arr[t] = v;
    __syncthreads();
    for (int off = 1; off < 512; off <<= 1) {
        unsigned int u = (t >= off) ? arr[t - off] : 0u;
        __syncthreads();
        arr[t] += u;
        __syncthreads();
    }
    if (t < NBKT) bktstart[t] = arr[t] - v;  // exclusive
    if (t == NBKT - 1) bktstart[NBKT] = arr[t];
}

// ---- pass 3: scatter edges to bucket segments; rank via LDS cursor atomics ----
// entry: hi32 = ew bits, lo32 = (d&127)<<24 | src
__global__ void __launch_bounds__(256) k_scatter(const int* __restrict__ src,
                                                 const int* __restrict__ dst,
                                                 const float* __restrict__ ew,
                                                 const unsigned int* __restrict__ colpre,
                                                 const unsigned int* __restrict__ bktstart,
                                                 unsigned long long* __restrict__ part) {
    __shared__ unsigned int ldsOff[NBKT];
    int tid = threadIdx.x, blk = blockIdx.x;
    for (int k = tid; k < NBKT; k += 256)
        ldsOff[k] = bktstart[k] + colpre[(size_t)blk * NBKT + k];
    __syncthreads();
    int base = blk * CHK;
    for (int i = tid; i < CHK; i += 256) {
        int e = base + i;
        if (e >= N_EDGES) continue;
        int s = src[e], d = dst[e];
        unsigned int pos = atomicAdd(&ldsOff[d >> BKT_SH], 1u);
        unsigned int lo = ((unsigned int)(d & (BKT_N - 1)) << 24) | (unsigned int)s;
        part[pos] = ((unsigned long long)__float_as_uint(ew[e]) << 32) | lo;
    }
}

// ---- pass 4: per-bucket LDS counting sort + deg/dinv + fp16 xs, fused ----
__global__ void __launch_bounds__(256) k_bucket(unsigned long long* __restrict__ part,
                                                const unsigned int* __restrict__ bktstart,
                                                const float* __restrict__ x,
                                                int* __restrict__ offs,
                                                float* __restrict__ dinv_g,
                                                uint4* __restrict__ xs) {
    __shared__ uint2 stage[SEG_CAP];
    __shared__ unsigned int cnt[BKT_N], cnt2[BKT_N], rowstart[BKT_N], sc[BKT_N];
    __shared__ float degf[BKT_N], dinv_l[BKT_N];
    int tid = threadIdx.x, k = blockIdx.x;
    unsigned int base = bktstart[k];
    unsigned int m = bktstart[k + 1] - base;
    if (m > SEG_CAP) m = SEG_CAP;  // 10-sigma margin; memory safety only
    if (tid < BKT_N) { cnt[tid] = 0u; cnt2[tid] = 0u; degf[tid] = 1.0f; }  // self loop
    __syncthreads();
    for (unsigned int i = tid; i < m; i += 256) {
        unsigned long long p = part[base + i];
        unsigned int lo = (unsigned int)p;
        unsigned int hi = (unsigned int)(p >> 32);
        stage[i] = make_uint2(lo, hi);
        unsigned int j = (lo >> 24) & (BKT_N - 1);
        atomicAdd(&cnt[j], 1u);
        atomicAdd(&degf[j], __uint_as_float(hi));
    }
    __syncthreads();
    if (tid < BKT_N) sc[tid] = cnt[tid];
    __syncthreads();
    for (int off = 1; off < BKT_N; off <<= 1) {
        unsigned int u = (tid >= (unsigned)off && tid < BKT_N) ? sc[tid - off] : 0u;
        __syncthreads();
        if (tid < BKT_N) sc[tid] += u;
        __syncthreads();
    }
    if (tid < BKT_N) rowstart[tid] = sc[tid] - cnt[tid];
    __syncthreads();

    int n0 = k * BKT_N;
    int nn = N_NODES - n0; if (nn > BKT_N) nn = BKT_N;

    if (tid < BKT_N) {
        float dv = rsqrtf(degf[tid]);
        dinv_l[tid] = dv;
        if (tid < nn) {
            dinv_g[n0 + tid] = dv;
            offs[n0 + tid] = (int)(base + rowstart[tid]);
        }
    }
    if (k == NBKT - 1 && tid == 0) offs[N_NODES] = N_EDGES;

    // sorted in-place write (reads from LDS stage — no hazard)
    for (unsigned int i = tid; i < m; i += 256) {
        uint2 v = stage[i];
        unsigned int j = (v.x >> 24) & (BKT_N - 1);
        unsigned int r = atomicAdd(&cnt2[j], 1u);
        part[base + rowstart[j] + r] = ((unsigned long long)v.y << 32) | v.x;
    }
    __syncthreads();

    // xs[n] = fp16(dinv[n] * x[n]) for this bucket's nodes (coalesced)
    for (int idx = tid; idx < nn * 6; idx += 256) {
        int j = idx / 6, c = idx % 6;
        int n = n0 + j;
        float di = dinv_l[j];
        const float4* xr = (const float4*)(x + (size_t)n * FP + c * 8);
        float4 a = xr[0], b2 = xr[1];
        __half2 h0 = __floats2half2_rn(di * a.x, di * a.y);
        __half2 h1 = __floats2half2_rn(di * a.z, di * a.w);
        __half2 h2 = __floats2half2_rn(di * b2.x, di * b2.y);
        __half2 h3 = __floats2half2_rn(di * b2.z, di * b2.w);
        uint4 o;
        o.x = *(unsigned int*)&h0; o.y = *(unsigned int*)&h1;
        o.z = *(unsigned int*)&h2; o.w = *(unsigned int*)&h3;
        xs[(size_t)n * 6 + c] = o;
    }
}

// ---- pass 5: simple gather, 12 lanes/node, register accumulate, no barriers ----
// xagg[n] = fp16( dinv[n] * (xs[n] + sum ew_e * xs[src_e]) )
__global__ void __launch_bounds__(256) k_gather(const uint2* __restrict__ xs2,
                                                const float* __restrict__ dinv,
                                                const int* __restrict__ offs,
                                                const unsigned long long* __restrict__ part,
                                                uint2* __restrict__ xagg2) {
    int t = blockIdx.x * 256 + threadIdx.x;
    if (t >= N_NODES * 12) return;
    int n = t / 12, c = t % 12;
    uint2 self = xs2[(size_t)n * 12 + c];
    float2 f0 = __half22float2(*(__half2*)&self.x);
    float2 f1 = __half22float2(*(__half2*)&self.y);
    float a0 = f0.x, a1 = f0.y, a2 = f1.x, a3 = f1.y;
    int b = offs[n], e = offs[n + 1];
    for (int kk = b; kk < e; kk++) {
        unsigned long long p = part[kk];
        float w = __uint_as_float((unsigned int)(p >> 32));
        int s = (int)((unsigned int)p & SRC_MASK);
        uint2 v = xs2[(size_t)s * 12 + c];
        float2 e0 = __half22float2(*(__half2*)&v.x);
        float2 e1 = __half22float2(*(__half2*)&v.y);
        a0 += w * e0.x; a1 += w * e0.y; a2 += w * e1.x; a3 += w * e1.y;
    }
    float di = dinv[n];
    __half2 o0 = __floats2half2_rn(di * a0, di * a1);
    __half2 o1 = __floats2half2_rn(di * a2, di * a3);
    uint2 o;
    o.x = *(unsigned int*)&o0; o.y = *(unsigned int*)&o1;
    xagg2[(size_t)n * 12 + c] = o;
}

// ---- pass 6: per-node fused epilogue (gates + attention + relu + linear) ----
// H0 == 0 => R gate dead; Z/Ht use only first F_OUT cols of lzW/lhW.
__global__ void k_node(const uint2* __restrict__ xagg2, const float* __restrict__ att,
                       const float* __restrict__ Wz, const float* __restrict__ bz,
                       const float* __restrict__ Wh, const float* __restrict__ bh,
                       const float* __restrict__ lzW, const float* __restrict__ lzb,
                       const float* __restrict__ lhW, const float* __restrict__ lhb,
                       const float* __restrict__ linW, const float* __restrict__ linb,
                       float* __restrict__ out) {
    int n = blockIdx.x * blockDim.x + threadIdx.x;
    if (n >= N_NODES) return;

    float a[PERIODS];
    float m = -1e30f;
    #pragma unroll
    for (int p = 0; p < PERIODS; p++) { a[p] = att[p]; m = fmaxf(m, a[p]); }
    float se = 0.f;
    #pragma unroll
    for (int p = 0; p < PERIODS; p++) { a[p] = __expf(a[p] - m); se += a[p]; }
    float inv = 1.f / se;
    #pragma unroll
    for (int p = 0; p < PERIODS; p++) a[p] *= inv;

    float row[FP];
    const uint2* xr = xagg2 + (size_t)n * 12;
    #pragma unroll
    for (int i = 0; i < 12; i++) {
        uint2 v = xr[i];
        float2 f0 = __half22float2(*(__half2*)&v.x);
        float2 f1 = __half22float2(*(__half2*)&v.y);
        row[4 * i] = f0.x; row[4 * i + 1] = f0.y;
        row[4 * i + 2] = f1.x; row[4 * i + 3] = f1.y;
    }

    float H[F_OUT];
    #pragma unroll
    for (int j = 0; j < F_OUT; j++) H[j] = 0.f;

    for (int p = 0; p < PERIODS; p++) {
        float gz[F_OUT], gh[F_OUT];
        #pragma unroll
        for (int j = 0; j < F_OUT; j++) { gz[j] = bz[j]; gh[j] = bh[j]; }
        #pragma unroll
        for (int f = 0; f < F_IN; f++) {
            float xv = row[f * PERIODS + p];
            #pragma unroll
            for (int j = 0; j < F_OUT; j++) {
                gz[j] += xv * Wz[f * F_OUT + j];
                gh[j] += xv * Wh[f * F_OUT + j];
            }
        }
        #pragma unroll
        for (int j = 0; j < F_OUT; j++) {
            float z = lzb[j], t2 = lhb[j];
            #pragma unroll
            for (int kk = 0; kk < F_OUT; kk++) {
                z  += gz[kk] * lzW[j * (2 * F_OUT) + kk];
                t2 += gh[kk] * lhW[j * (2 * F_OUT) + kk];
            }
            float Z = 1.f / (1.f + __expf(-z));
            H[j] += a[p] * (1.f - Z) * tanhf(t2);
        }
    }

    float* op = out + (size_t)n * PERIODS;
    #pragma unroll
    for (int q = 0; q < PERIODS; q++) {
        float acc = linb[q];
        #pragma unroll
        for (int j = 0; j < F_OUT; j++)
            acc += fmaxf(H[j], 0.f) * linW[q * F_OUT + j];
        op[q] = acc;
    }
}

extern "C" void kernel_launch(void* const* d_in, const int* in_sizes, int n_in,
                              void* d_out, int out_size, void* d_ws, size_t ws_size,
                              hipStream_t stream) {
    const float* x    = (const float*)d_in[0];
    const int*   ei   = (const int*)d_in[1];
    const float* ew   = (const float*)d_in[2];
    const float* att  = (const float*)d_in[3];
    const float* Wz   = (const float*)d_in[4];
    const float* bz   = (const float*)d_in[5];
    // d_in[6]=Wr, d_in[7]=br : dead (H0 == 0)
    const float* Wh   = (const float*)d_in[8];
    const float* bh   = (const float*)d_in[9];
    const float* lzW  = (const float*)d_in[10];
    const float* lzb  = (const float*)d_in[11];
    // d_in[12]=lrW, d_in[13]=lrb : dead
    const float* lhW  = (const float*)d_in[14];
    const float* lhb  = (const float*)d_in[15];
    const float* linW = (const float*)d_in[16];
    const float* linb = (const float*)d_in[17];
    float* out = (float*)d_out;

    // ws layout (~23.4 MB): part, xs (fp16 dinv*x), xagg (fp16), hist(=colpre in place),
    // dinv, offs, bktstart, tot
    unsigned long long* part = (unsigned long long*)d_ws;            // E * 8B (sorted in place)
    uint4* xs = (uint4*)(part + N_EDGES);                            // N*6 uint4 = 4.8 MB
    uint2* xagg2 = (uint2*)(xs + (size_t)N_NODES * 6);               // N*12 uint2 = 4.8 MB
    unsigned int* hist = (unsigned int*)(xagg2 + (size_t)N_NODES * 12); // NCHK*NBKT u32
    float* dinv = (float*)(hist + (size_t)NCHK * NBKT);              // N floats
    int*   offs = (int*)(dinv + N_NODES);                            // N+1 ints
    unsigned int* bktstart = (unsigned int*)(offs + N_NODES + 1);    // NBKT+1 u32
    unsigned int* tot = bktstart + NBKT + 1;                         // NBKT u32

    const int* srcp = ei;
    const int* dstp = ei + N_EDGES;

    k_hist<<<NCHK, 256, 0, stream>>>(dstp, hist);
    k_colscan<<<NBKT, 512, 0, stream>>>(hist, tot);
    k_topscan<<<1, 512, 0, stream>>>(tot, bktstart);
    k_scatter<<<NCHK, 256, 0, stream>>>(srcp, dstp, ew, hist, bktstart, part);
    k_bucket<<<NBKT, 256, 0, stream>>>(part, bktstart, x, offs, dinv, xs);
    k_gather<<<(N_NODES * 12 + 255) / 256, 256, 0, stream>>>(
        (const uint2*)xs, dinv, offs, part, xagg2);
    k_node<<<(N_NODES + 255) / 256, 256, 0, stream>>>(xagg2, att, Wz, bz, Wh, bh,
                                                      lzW, lzb, lhW, lhb, linW, linb, out);
}